// Round 1
// baseline (67.535 us; speedup 1.0000x reference)
//
#include <hip/hip_runtime.h>

#define H 1024
#define W 1024
#define NB 8
#define PAD 4
#define TY 16
#define NTHREADS 256
#define LDSW (W + 2 * PAD) /* 1032 */

__global__ void ncc_zero(double* acc) { *acc = 0.0; }

__global__ void ncc_finalize(const double* __restrict__ acc, float* __restrict__ out) {
    out[0] = 1.0f - (float)(*acc * (1.0 / (double)((size_t)NB * H * W)));
}

__global__ __launch_bounds__(NTHREADS) void ncc_main(
    const float* __restrict__ Jg,  // y_pred
    const float* __restrict__ Ig,  // y_true
    double* __restrict__ acc)
{
    __shared__ float vs[5][LDSW];

    const int b  = blockIdx.x;
    const int y0 = blockIdx.y * TY;
    const int t  = threadIdx.x;
    const int x0 = t * 4;

    const float* Ib = Ig + (size_t)b * H * W;
    const float* Jb = Jg + (size_t)b * H * W;

    // zero the LDS halo pads once (cols [0,4) and [1028,1032) of each of 5 arrays)
    if (t < 40) {
        int q = t >> 3, j = t & 7;
        vs[q][(j < 4) ? j : (W + PAD + (j - 4))] = 0.0f;
    }

    float sI[4]  = {0, 0, 0, 0};
    float sJ[4]  = {0, 0, 0, 0};
    float sII[4] = {0, 0, 0, 0};
    float sJJ[4] = {0, 0, 0, 0};
    float sIJ[4] = {0, 0, 0, 0};

    // initial vertical window for output row y0: input rows y0-4 .. y0+4 (zero-padded)
    for (int r = y0 - PAD; r <= y0 + PAD; ++r) {
        if (r >= 0 && r < H) {
            float4 iv = *(const float4*)(Ib + (size_t)r * W + x0);
            float4 jv = *(const float4*)(Jb + (size_t)r * W + x0);
            float fi[4] = {iv.x, iv.y, iv.z, iv.w};
            float fj[4] = {jv.x, jv.y, jv.z, jv.w};
            #pragma unroll
            for (int c = 0; c < 4; ++c) {
                sI[c]  += fi[c];
                sJ[c]  += fj[c];
                sII[c] += fi[c] * fi[c];
                sJJ[c] += fj[c] * fj[c];
                sIJ[c] += fi[c] * fj[c];
            }
        }
    }

    const float inv = 1.0f / 81.0f;
    float accv = 0.0f;

    for (int y = y0; y < y0 + TY; ++y) {
        // publish this row's vertical sums (aligned float4 stores, conflict-free)
        *(float4*)&vs[0][PAD + x0] = make_float4(sI[0],  sI[1],  sI[2],  sI[3]);
        *(float4*)&vs[1][PAD + x0] = make_float4(sJ[0],  sJ[1],  sJ[2],  sJ[3]);
        *(float4*)&vs[2][PAD + x0] = make_float4(sII[0], sII[1], sII[2], sII[3]);
        *(float4*)&vs[3][PAD + x0] = make_float4(sJJ[0], sJJ[1], sJJ[2], sJJ[3]);
        *(float4*)&vs[4][PAD + x0] = make_float4(sIJ[0], sIJ[1], sIJ[2], sIJ[3]);
        __syncthreads();

        // horizontal 9-tap sums via prefix-slide over 12 staged columns
        float h[5][4];
        #pragma unroll
        for (int q = 0; q < 5; ++q) {
            float4 a  = *(const float4*)&vs[q][x0];       // cols x0-4 .. x0-1 (lds idx x0..x0+3)
            float4 bb = *(const float4*)&vs[q][x0 + 4];
            float4 cc = *(const float4*)&vs[q][x0 + 8];
            float v[12] = {a.x,  a.y,  a.z,  a.w,
                           bb.x, bb.y, bb.z, bb.w,
                           cc.x, cc.y, cc.z, cc.w};
            float s = v[0] + v[1] + v[2] + v[3] + v[4] + v[5] + v[6] + v[7] + v[8];
            h[q][0] = s;
            s += v[9]  - v[0]; h[q][1] = s;
            s += v[10] - v[1]; h[q][2] = s;
            s += v[11] - v[2]; h[q][3] = s;
        }

        // per-pixel cc
        #pragma unroll
        for (int c = 0; c < 4; ++c) {
            float uI    = h[0][c] * inv;
            float uJ    = h[1][c] * inv;
            float cross = h[4][c] * inv - uI * uJ;
            float Ivar  = h[2][c] * inv - uI * uI;
            float Jvar  = h[3][c] * inv - uJ * uJ;
            accv += cross * rsqrtf(fmaxf(Ivar * Jvar, 1e-7f));
        }

        __syncthreads();  // reads done before next iteration's vs overwrite

        // slide vertical window: add row y+5, subtract row y-4
        {
            const int ra = y + PAD + 1;
            const int rs = y - PAD;
            if (ra < H) {
                float4 iv = *(const float4*)(Ib + (size_t)ra * W + x0);
                float4 jv = *(const float4*)(Jb + (size_t)ra * W + x0);
                float fi[4] = {iv.x, iv.y, iv.z, iv.w};
                float fj[4] = {jv.x, jv.y, jv.z, jv.w};
                #pragma unroll
                for (int c = 0; c < 4; ++c) {
                    sI[c]  += fi[c];
                    sJ[c]  += fj[c];
                    sII[c] += fi[c] * fi[c];
                    sJJ[c] += fj[c] * fj[c];
                    sIJ[c] += fi[c] * fj[c];
                }
            }
            if (rs >= 0) {
                float4 iv = *(const float4*)(Ib + (size_t)rs * W + x0);
                float4 jv = *(const float4*)(Jb + (size_t)rs * W + x0);
                float fi[4] = {iv.x, iv.y, iv.z, iv.w};
                float fj[4] = {jv.x, jv.y, jv.z, jv.w};
                #pragma unroll
                for (int c = 0; c < 4; ++c) {
                    sI[c]  -= fi[c];
                    sJ[c]  -= fj[c];
                    sII[c] -= fi[c] * fi[c];
                    sJJ[c] -= fj[c] * fj[c];
                    sIJ[c] -= fi[c] * fj[c];
                }
            }
        }
    }

    // wave reduce (64 lanes), one double atomic per wave
    #pragma unroll
    for (int off = 32; off > 0; off >>= 1)
        accv += __shfl_down(accv, off);
    if ((t & 63) == 0)
        atomicAdd(acc, (double)accv);
}

extern "C" void kernel_launch(void* const* d_in, const int* in_sizes, int n_in,
                              void* d_out, int out_size, void* d_ws, size_t ws_size,
                              hipStream_t stream) {
    const float* y_pred = (const float*)d_in[0];  // Ji
    const float* y_true = (const float*)d_in[1];  // Ii
    float* out = (float*)d_out;
    double* acc = (double*)d_ws;

    ncc_zero<<<dim3(1), dim3(1), 0, stream>>>(acc);
    dim3 grid(NB, H / TY);  // 8 x 64 = 512 blocks
    ncc_main<<<grid, dim3(NTHREADS), 0, stream>>>(y_pred, y_true, acc);
    ncc_finalize<<<dim3(1), dim3(1), 0, stream>>>(acc, out);
}